// Round 4
// baseline (951.523 us; speedup 1.0000x reference)
//
#include <hip/hip_runtime.h>

typedef __attribute__((ext_vector_type(8))) short bf16x8;
typedef __attribute__((ext_vector_type(4))) float f32x4;
using u16 = unsigned short;

#define DEVINL static __device__ __forceinline__

DEVINL u16 f2bf(float f) {
  union { float f; unsigned u; } v; v.f = f;
  unsigned r = v.u + 0x7FFFu + ((v.u >> 16) & 1u);   // RNE
  return (u16)(r >> 16);
}

DEVINL void gload16(const u16* g, u16* l) {
  __builtin_amdgcn_global_load_lds((const __attribute__((address_space(1))) void*)g,
                                   (__attribute__((address_space(3))) void*)l,
                                   16, 0, 0);
}

// ---------------- GroupNorm stats: two-stage, 512-block parallel ----------------
__global__ __launch_bounds__(256) void gn_stats1_k(const float* __restrict__ x,
                                                   float* __restrict__ psum,
                                                   float* __restrict__ psumsq) {
  const int blk = blockIdx.x;
  const float4* p4 = (const float4*)(x + (size_t)(blk >> 4) * (64 * 4096))
                     + (size_t)(blk & 15) * 4096;
  float s = 0.f, ss = 0.f;
  #pragma unroll
  for (int i = 0; i < 16; ++i) {
    float4 v = p4[i*256 + threadIdx.x];
    s  += v.x + v.y + v.z + v.w;
    ss += v.x*v.x + v.y*v.y + v.z*v.z + v.w*v.w;
  }
  #pragma unroll
  for (int off = 32; off > 0; off >>= 1) {
    s  += __shfl_down(s, off, 64);
    ss += __shfl_down(ss, off, 64);
  }
  __shared__ float rs[4], rss[4];
  const int lane = threadIdx.x & 63, w = threadIdx.x >> 6;
  if (lane == 0) { rs[w] = s; rss[w] = ss; }
  __syncthreads();
  if (threadIdx.x == 0) {
    psum[blk]   = rs[0]+rs[1]+rs[2]+rs[3];
    psumsq[blk] = rss[0]+rss[1]+rss[2]+rss[3];
  }
}

__global__ void gn_stats2_k(const float* __restrict__ psum,
                            const float* __restrict__ psumsq,
                            float* __restrict__ stats) {
  const int bg = threadIdx.x;   // 32 threads
  if (bg >= 32) return;
  float s = 0.f, ss = 0.f;
  #pragma unroll
  for (int p = 0; p < 16; ++p) { s += psum[bg*16+p]; ss += psumsq[bg*16+p]; }
  const float inv = 1.f / 262144.f;
  float mean = s * inv;
  float var  = ss * inv - mean * mean;
  stats[bg*2]   = mean;
  stats[bg*2+1] = rsqrtf(var + 1e-5f);
}

// Normalize + transpose: x[b][c][n] -> hT[b][n][c] bf16.
__global__ __launch_bounds__(256) void gn_apply_k(const float* __restrict__ x,
                                                  const float* __restrict__ gamma,
                                                  const float* __restrict__ beta,
                                                  const float* __restrict__ stats,
                                                  u16* __restrict__ hT) {
  __shared__ u16 tile[64][65];
  const int b = blockIdx.z, ct = blockIdx.y, nt = blockIdx.x;
  const int t = threadIdx.x;
  const float mean = stats[(b*8 + ct)*2 + 0];
  const float rstd = stats[(b*8 + ct)*2 + 1];
  const float* xb = x + ((size_t)b*512 + (size_t)ct*64) * 4096 + nt*64;
  #pragma unroll
  for (int i = 0; i < 16; ++i) {
    int idx = i*256 + t; int cl = idx >> 6, nl = idx & 63;
    float v  = xb[(size_t)cl*4096 + nl];
    float hn = (v - mean) * rstd * gamma[ct*64 + cl] + beta[ct*64 + cl];
    tile[cl][nl] = f2bf(hn);
  }
  __syncthreads();
  u16* o = hT + ((size_t)b*4096 + (size_t)nt*64) * 512 + ct*64;
  #pragma unroll
  for (int i = 0; i < 16; ++i) {
    int idx = i*256 + t; int nl = idx >> 6, cl = idx & 63;
    o[(size_t)nl*512 + cl] = tile[cl][nl];
  }
}

__global__ __launch_bounds__(256) void cast_w_k(const float* __restrict__ wq,
                                                const float* __restrict__ wp,
                                                u16* __restrict__ wqb,
                                                u16* __restrict__ wpb) {
  int i = blockIdx.x*256 + threadIdx.x;
  if (i < 1536*512) wqb[i] = f2bf(wq[i]);
  if (i < 512*512)  wpb[i] = f2bf(wp[i]);
}

// ---------------- NT GEMM core (m97 structure, 128x128, 4 waves) ----------------
DEVINL void gemm_nt_core(const u16* __restrict__ A, int lda,
                         const u16* __restrict__ B, int ldb,
                         int K, u16* As, u16* Bs, f32x4 acc[4][4]) {
  const int tid = threadIdx.x;
  const int lane = tid & 63, w = tid >> 6;
  const int wr = w >> 1, wc = w & 1;
  const int fr = lane & 15, fk = lane >> 4;
  for (int kt = 0; kt < K; kt += 64) {
    #pragma unroll
    for (int i = 0; i < 4; ++i) {
      int ch = i*256 + tid;
      int row = ch >> 3, kc = ch & 7;
      gload16(A + (size_t)row*lda + kt + kc*8, As + ch*8);
      gload16(B + (size_t)row*ldb + kt + kc*8, Bs + ch*8);
    }
    __syncthreads();
    #pragma unroll
    for (int kk = 0; kk < 2; ++kk) {
      bf16x8 af[4], bfg[4];
      #pragma unroll
      for (int i = 0; i < 4; ++i)
        af[i] = *(const bf16x8*)(As + ((wr*64 + i*16 + fr)*64 + kk*32 + fk*8));
      #pragma unroll
      for (int j = 0; j < 4; ++j)
        bfg[j] = *(const bf16x8*)(Bs + ((wc*64 + j*16 + fr)*64 + kk*32 + fk*8));
      #pragma unroll
      for (int i = 0; i < 4; ++i)
        #pragma unroll
        for (int j = 0; j < 4; ++j)
          acc[i][j] = __builtin_amdgcn_mfma_f32_16x16x32_bf16(af[i], bfg[j], acc[i][j], 0, 0, 0);
    }
    __syncthreads();
  }
}

#define GEMM_PROLOGUE() \
  __shared__ __align__(16) u16 As[128*64]; \
  __shared__ __align__(16) u16 Bs[128*64]; \
  f32x4 acc[4][4] = {}; \
  const int tid = threadIdx.x; \
  const int lane = tid & 63, w = tid >> 6; \
  const int wr = w >> 1, wc = w & 1; \
  const int fr = lane & 15, fk = lane >> 4; \
  (void)lane;

__global__ __launch_bounds__(256) void k_qkv(const u16* __restrict__ hT,
                                             const u16* __restrict__ wq,
                                             const float* __restrict__ bqkv,
                                             u16* __restrict__ qT, u16* __restrict__ kT,
                                             u16* __restrict__ vb) {
  GEMM_PROLOGUE();
  const int bz = blockIdx.z;
  const int rowBase = blockIdx.y * 128, colBase = blockIdx.x * 128;
  gemm_nt_core(hT + ((size_t)bz*4096 + rowBase)*512, 512,
               wq + (size_t)colBase*512, 512, 512, As, Bs, acc);
  #pragma unroll
  for (int i = 0; i < 4; ++i)
    #pragma unroll
    for (int j = 0; j < 4; ++j)
      #pragma unroll
      for (int r = 0; r < 4; ++r) {
        int n = rowBase + wr*64 + i*16 + fk*4 + r;
        int o = colBase + wc*64 + j*16 + fr;
        u16 u = f2bf(acc[i][j][r] + bqkv[o]);
        if (o < 512)       qT[((size_t)bz*4096 + n)*512 + o]          = u;
        else if (o < 1024) kT[((size_t)bz*4096 + n)*512 + (o - 512)]  = u;
        else               vb[((size_t)bz*512 + (o - 1024))*4096 + n] = u;
      }
}

// ---------------- Scores: 256x256 tile, BK=32, 2-buf 2-phase (2 blocks/CU) ------
// 8 waves (2M x 4N). stage(t+1) right after barrier; __syncthreads per K-tile
// (compiler emits vmcnt(0)+barrier); co-resident block hides the drain.
// LDS read swizzle: 16B-slot ^= (row&3); inverse-swizzled global source.
DEVINL void stage_qk2(const u16* __restrict__ qa, const u16* __restrict__ ka,
                      int kt, u16* As, u16* Bs, int tid) {
  #pragma unroll
  for (int q = 0; q < 2; ++q) {
    int c = q*512 + tid;                 // 1024 chunks of 16B per operand
    int row = c >> 2, slot = c & 3;
    int sslot = slot ^ (row & 3);        // inverse swizzle on global source
    gload16(qa + (size_t)row*512 + kt + sslot*8, As + c*8);
    gload16(ka + (size_t)row*512 + kt + sslot*8, Bs + c*8);
  }
}

__global__ __launch_bounds__(512, 4) void k_scores256(const u16* __restrict__ qT,
                                                      const u16* __restrict__ kT,
                                                      u16* __restrict__ E,
                                                      float* __restrict__ lsum) {
  __shared__ __align__(16) u16 As[2][256*32];   // 32 KB
  __shared__ __align__(16) u16 Bs[2][256*32];   // 32 KB
  f32x4 acc[8][4] = {};
  const int tid = threadIdx.x;
  const int lane = tid & 63, w = tid >> 6;
  const int wr = w >> 2, wc = w & 3;            // 2M x 4N wave grid
  const int fr = lane & 15, fk = lane >> 4;
  const int bz = blockIdx.z;
  // T1: bijective XCD swizzle (256 blocks/slice, 32 per XCD, grouped by Q-row)
  int f = blockIdx.y * 16 + blockIdx.x;
  int L = (f & 7) * 32 + (f >> 3);
  const int rowBase = (L >> 4) * 256, colBase = (L & 15) * 256;
  const u16* qa = qT + (size_t)bz*4096*512 + (size_t)rowBase*512;
  const u16* ka = kT + (size_t)bz*4096*512 + (size_t)colBase*512;
  u16* Eb = E + (size_t)bz*4096*4096;
  float* ls = lsum + (size_t)bz*4096;

  stage_qk2(qa, ka, 0, As[0], Bs[0], tid);

  #pragma unroll 1
  for (int t = 0; t < 16; ++t) {
    __syncthreads();                      // drains vmcnt(0): tile t resident
    if (t < 15)
      stage_qk2(qa, ka, (t+1)*32, As[(t+1)&1], Bs[(t+1)&1], tid);
    const u16* Ab = As[t & 1];
    const u16* Bb = Bs[t & 1];
    bf16x8 af[8], bfg[4];
    #pragma unroll
    for (int i = 0; i < 8; ++i) {
      int row = wr*128 + i*16 + fr;
      af[i] = *(const bf16x8*)(Ab + row*32 + ((fk ^ row) & 3)*8);
    }
    #pragma unroll
    for (int j = 0; j < 4; ++j) {
      int row = wc*64 + j*16 + fr;
      bfg[j] = *(const bf16x8*)(Bb + row*32 + ((fk ^ row) & 3)*8);
    }
    __builtin_amdgcn_s_setprio(1);
    #pragma unroll
    for (int i = 0; i < 8; ++i)
      #pragma unroll
      for (int j = 0; j < 4; ++j)
        acc[i][j] = __builtin_amdgcn_mfma_f32_16x16x32_bf16(af[i], bfg[j], acc[i][j], 0, 0, 0);
    __builtin_amdgcn_s_setprio(0);
  }

  const float scale = 0.04419417382415922f;  // 512^-0.5
  #pragma unroll
  for (int i = 0; i < 8; ++i)
    #pragma unroll
    for (int r = 0; r < 4; ++r) {
      int nl = rowBase + wr*128 + i*16 + fk*4 + r;
      float s = 0.f;
      #pragma unroll
      for (int j = 0; j < 4; ++j) {
        int m = colBase + wc*64 + j*16 + fr;
        float e = __expf(acc[i][j][r] * scale);
        Eb[(size_t)nl*4096 + m] = f2bf(e);
        s += e;
      }
      s += __shfl_xor(s, 1, 64);
      s += __shfl_xor(s, 2, 64);
      s += __shfl_xor(s, 4, 64);
      s += __shfl_xor(s, 8, 64);
      if (fr == 0) atomicAdd(&ls[nl], s);
    }
}

// Old 128^2 scores kernel kept for the chunked fallback path.
__global__ __launch_bounds__(256) void k_scores(const u16* __restrict__ qT,
                                                const u16* __restrict__ kT,
                                                u16* __restrict__ E,
                                                float* __restrict__ lsum,
                                                long long qkStride, long long eStride,
                                                int lsStride) {
  GEMM_PROLOGUE();
  const int bz = blockIdx.z;
  const u16* q0 = qT + (size_t)bz * qkStride;
  const u16* k0 = kT + (size_t)bz * qkStride;
  u16* Eb = E + (size_t)bz * eStride;
  float* ls = lsum + (size_t)bz * lsStride;
  const int rowBase = blockIdx.y * 128, colBase = blockIdx.x * 128;
  gemm_nt_core(q0 + (size_t)rowBase*512, 512, k0 + (size_t)colBase*512, 512,
               512, As, Bs, acc);
  const float scale = 0.04419417382415922f;
  #pragma unroll
  for (int i = 0; i < 4; ++i)
    #pragma unroll
    for (int r = 0; r < 4; ++r) {
      int nl = rowBase + wr*64 + i*16 + fk*4 + r;
      float s = 0.f;
      #pragma unroll
      for (int j = 0; j < 4; ++j) {
        int m = colBase + wc*64 + j*16 + fr;
        float e = __expf(acc[i][j][r] * scale);
        Eb[(size_t)nl*4096 + m] = f2bf(e);
        s += e;
      }
      s += __shfl_xor(s, 1, 64);
      s += __shfl_xor(s, 2, 64);
      s += __shfl_xor(s, 4, 64);
      s += __shfl_xor(s, 8, 64);
      if (fr == 0) atomicAdd(&ls[nl], s);
    }
}

// PV: out[nl][d] = (sum_m E[nl][m] * v[d][m]) / lsum[nl].
__global__ __launch_bounds__(256) void k_pv(const u16* __restrict__ E,
                                            const u16* __restrict__ vb,
                                            const float* __restrict__ lsum,
                                            u16* __restrict__ attnb,
                                            long long eStride, long long vStride,
                                            int lsStride, long long aStride,
                                            int doSwz) {
  GEMM_PROLOGUE();
  const int bz = blockIdx.z;
  const u16* Eb = E + (size_t)bz * eStride;
  const u16* vbb = vb + (size_t)bz * vStride;
  const float* ls = lsum + (size_t)bz * lsStride;
  u16* ab = attnb + (size_t)bz * aStride;
  int rowT = blockIdx.y, colT = blockIdx.x;
  if (doSwz) {             // T1: 128 blocks/slice -> 16 per XCD, grouped by E-row
    int f = blockIdx.y * 4 + blockIdx.x;
    int L = (f & 7) * 16 + (f >> 3);
    rowT = L >> 2; colT = L & 3;
  }
  const int rowBase = rowT * 128, colBase = colT * 128;
  gemm_nt_core(Eb + (size_t)rowBase*4096, 4096, vbb + (size_t)colBase*4096, 4096,
               4096, As, Bs, acc);
  #pragma unroll
  for (int i = 0; i < 4; ++i)
    #pragma unroll
    for (int r = 0; r < 4; ++r) {
      int nl = rowBase + wr*64 + i*16 + fk*4 + r;
      float rinv = 1.0f / ls[nl];
      #pragma unroll
      for (int j = 0; j < 4; ++j) {
        int d = colBase + wc*64 + j*16 + fr;
        ab[(size_t)nl*512 + d] = f2bf(acc[i][j][r] * rinv);
      }
    }
}

__global__ __launch_bounds__(256) void k_proj(const u16* __restrict__ wp,
                                              const u16* __restrict__ attn,
                                              const float* __restrict__ bproj,
                                              const float* __restrict__ x,
                                              float* __restrict__ out) {
  GEMM_PROLOGUE();
  const int bz = blockIdx.z;
  const int rowBase = blockIdx.y * 128, colBase = blockIdx.x * 128;
  gemm_nt_core(wp + (size_t)rowBase*512, 512,
               attn + ((size_t)bz*4096 + colBase)*512, 512, 512, As, Bs, acc);
  #pragma unroll
  for (int i = 0; i < 4; ++i)
    #pragma unroll
    for (int j = 0; j < 4; ++j)
      #pragma unroll
      for (int r = 0; r < 4; ++r) {
        int o = rowBase + wr*64 + i*16 + fk*4 + r;
        int n = colBase + wc*64 + j*16 + fr;
        size_t idx = ((size_t)bz*512 + o)*4096 + n;
        out[idx] = acc[i][j][r] + bproj[o] + x[idx];
      }
}

extern "C" void kernel_launch(void* const* d_in, const int* in_sizes, int n_in,
                              void* d_out, int out_size, void* d_ws, size_t ws_size,
                              hipStream_t stream) {
  const float* x      = (const float*)d_in[0];
  const float* gamma  = (const float*)d_in[1];
  const float* beta   = (const float*)d_in[2];
  const float* w_qkv  = (const float*)d_in[3];
  const float* b_qkv  = (const float*)d_in[4];
  const float* w_proj = (const float*)d_in[5];
  const float* b_proj = (const float*)d_in[6];
  float* out = (float*)d_out;
  char* ws = (char*)d_ws;

  size_t off = 0;
  u16* wqb   = (u16*)(ws + off); off += (size_t)1536*512*2;
  u16* wpb   = (u16*)(ws + off); off += (size_t)512*512*2;
  float* stats = (float*)(ws + off); off += 256;
  float* psum  = (float*)(ws + off); off += 512*4;
  float* psumsq= (float*)(ws + off); off += 512*4;
  float* lsum  = (float*)(ws + off); off += (size_t)4*4096*4;
  u16* hT    = (u16*)(ws + off);                      // reused as attn_out after QKV
  u16* attn  = hT;
  off += (size_t)4*4096*512*2;
  u16* qT    = (u16*)(ws + off); off += (size_t)4*4096*512*2;
  u16* kT    = (u16*)(ws + off); off += (size_t)4*4096*512*2;
  u16* vb    = (u16*)(ws + off); off += (size_t)4*4096*512*2;
  u16* E     = (u16*)(ws + off);
  size_t avail = ws_size > off ? ws_size - off : 0;
  const size_t fullE = (size_t)4*4096*4096*2;

  gn_stats1_k<<<512, 256, 0, stream>>>(x, psum, psumsq);
  gn_stats2_k<<<1, 32, 0, stream>>>(psum, psumsq, stats);
  gn_apply_k<<<dim3(64, 8, 4), 256, 0, stream>>>(x, gamma, beta, stats, hT);
  cast_w_k<<<3072, 256, 0, stream>>>(w_qkv, w_proj, wqb, wpb);
  k_qkv<<<dim3(12, 32, 4), 256, 0, stream>>>(hT, wqb, b_qkv, qT, kT, vb);

  if (avail >= fullE) {
    (void)hipMemsetAsync(lsum, 0, (size_t)4*4096*sizeof(float), stream);
    k_scores256<<<dim3(16, 16, 4), 512, 0, stream>>>(qT, kT, E, lsum);
    k_pv<<<dim3(4, 32, 4), 256, 0, stream>>>(
        E, vb, lsum, attn, 4096LL*4096, 512LL*4096, 4096, 4096LL*512, 1);
  } else {
    int CH = 4096;
    while (CH > 128 && (size_t)CH*4096*2 > avail) CH >>= 1;
    for (int b = 0; b < 4; ++b) {
      for (int c0 = 0; c0 < 4096; c0 += CH) {
        (void)hipMemsetAsync(lsum, 0, (size_t)CH * sizeof(float), stream);
        k_scores<<<dim3(32, CH/128, 1), 256, 0, stream>>>(
            qT + ((size_t)b*4096 + c0)*512, kT + (size_t)b*4096*512, E, lsum, 0, 0, 0);
        k_pv<<<dim3(4, CH/128, 1), 256, 0, stream>>>(
            E, vb + (size_t)b*512*4096, lsum, attn + ((size_t)b*4096 + c0)*512, 0, 0, 0, 0, 0);
      }
    }
  }
  k_proj<<<dim3(32, 4, 4), 256, 0, stream>>>(wpb, attn, b_proj, x, out);
}

// Round 5
// 314.493 us; speedup vs baseline: 3.0256x; 3.0256x over previous
//
#include <hip/hip_runtime.h>

typedef __attribute__((ext_vector_type(8))) short bf16x8;
typedef __attribute__((ext_vector_type(4))) float f32x4;
using u16 = unsigned short;

#define DEVINL static __device__ __forceinline__

DEVINL u16 f2bf(float f) {
  union { float f; unsigned u; } v; v.f = f;
  unsigned r = v.u + 0x7FFFu + ((v.u >> 16) & 1u);   // RNE
  return (u16)(r >> 16);
}

DEVINL void gload16(const u16* g, u16* l) {
  __builtin_amdgcn_global_load_lds((const __attribute__((address_space(1))) void*)g,
                                   (__attribute__((address_space(3))) void*)l,
                                   16, 0, 0);
}

// ---------------- GroupNorm stats: two-stage, 512-block parallel ----------------
__global__ __launch_bounds__(256) void gn_stats1_k(const float* __restrict__ x,
                                                   float* __restrict__ psum,
                                                   float* __restrict__ psumsq) {
  const int blk = blockIdx.x;
  const float4* p4 = (const float4*)(x + (size_t)(blk >> 4) * (64 * 4096))
                     + (size_t)(blk & 15) * 4096;
  float s = 0.f, ss = 0.f;
  #pragma unroll
  for (int i = 0; i < 16; ++i) {
    float4 v = p4[i*256 + threadIdx.x];
    s  += v.x + v.y + v.z + v.w;
    ss += v.x*v.x + v.y*v.y + v.z*v.z + v.w*v.w;
  }
  #pragma unroll
  for (int off = 32; off > 0; off >>= 1) {
    s  += __shfl_down(s, off, 64);
    ss += __shfl_down(ss, off, 64);
  }
  __shared__ float rs[4], rss[4];
  const int lane = threadIdx.x & 63, w = threadIdx.x >> 6;
  if (lane == 0) { rs[w] = s; rss[w] = ss; }
  __syncthreads();
  if (threadIdx.x == 0) {
    psum[blk]   = rs[0]+rs[1]+rs[2]+rs[3];
    psumsq[blk] = rss[0]+rss[1]+rss[2]+rss[3];
  }
}

__global__ void gn_stats2_k(const float* __restrict__ psum,
                            const float* __restrict__ psumsq,
                            float* __restrict__ stats) {
  const int bg = threadIdx.x;   // 32 threads
  if (bg >= 32) return;
  float s = 0.f, ss = 0.f;
  #pragma unroll
  for (int p = 0; p < 16; ++p) { s += psum[bg*16+p]; ss += psumsq[bg*16+p]; }
  const float inv = 1.f / 262144.f;
  float mean = s * inv;
  float var  = ss * inv - mean * mean;
  stats[bg*2]   = mean;
  stats[bg*2+1] = rsqrtf(var + 1e-5f);
}

// Normalize + transpose: x[b][c][n] -> hT[b][n][c] bf16.
__global__ __launch_bounds__(256) void gn_apply_k(const float* __restrict__ x,
                                                  const float* __restrict__ gamma,
                                                  const float* __restrict__ beta,
                                                  const float* __restrict__ stats,
                                                  u16* __restrict__ hT) {
  __shared__ u16 tile[64][65];
  const int b = blockIdx.z, ct = blockIdx.y, nt = blockIdx.x;
  const int t = threadIdx.x;
  const float mean = stats[(b*8 + ct)*2 + 0];
  const float rstd = stats[(b*8 + ct)*2 + 1];
  const float* xb = x + ((size_t)b*512 + (size_t)ct*64) * 4096 + nt*64;
  #pragma unroll
  for (int i = 0; i < 16; ++i) {
    int idx = i*256 + t; int cl = idx >> 6, nl = idx & 63;
    float v  = xb[(size_t)cl*4096 + nl];
    float hn = (v - mean) * rstd * gamma[ct*64 + cl] + beta[ct*64 + cl];
    tile[cl][nl] = f2bf(hn);
  }
  __syncthreads();
  u16* o = hT + ((size_t)b*4096 + (size_t)nt*64) * 512 + ct*64;
  #pragma unroll
  for (int i = 0; i < 16; ++i) {
    int idx = i*256 + t; int nl = idx >> 6, cl = idx & 63;
    o[(size_t)nl*512 + cl] = tile[cl][nl];
  }
}

__global__ __launch_bounds__(256) void cast_w_k(const float* __restrict__ wq,
                                                const float* __restrict__ wp,
                                                u16* __restrict__ wqb,
                                                u16* __restrict__ wpb) {
  int i = blockIdx.x*256 + threadIdx.x;
  if (i < 1536*512) wqb[i] = f2bf(wq[i]);
  if (i < 512*512)  wpb[i] = f2bf(wp[i]);
}

// ---------------- NT GEMM core (m97 structure, 128x128, 4 waves) ----------------
DEVINL void gemm_nt_core(const u16* __restrict__ A, int lda,
                         const u16* __restrict__ B, int ldb,
                         int K, u16* As, u16* Bs, f32x4 acc[4][4]) {
  const int tid = threadIdx.x;
  const int lane = tid & 63, w = tid >> 6;
  const int wr = w >> 1, wc = w & 1;
  const int fr = lane & 15, fk = lane >> 4;
  for (int kt = 0; kt < K; kt += 64) {
    #pragma unroll
    for (int i = 0; i < 4; ++i) {
      int ch = i*256 + tid;
      int row = ch >> 3, kc = ch & 7;
      gload16(A + (size_t)row*lda + kt + kc*8, As + ch*8);
      gload16(B + (size_t)row*ldb + kt + kc*8, Bs + ch*8);
    }
    __syncthreads();
    #pragma unroll
    for (int kk = 0; kk < 2; ++kk) {
      bf16x8 af[4], bfg[4];
      #pragma unroll
      for (int i = 0; i < 4; ++i)
        af[i] = *(const bf16x8*)(As + ((wr*64 + i*16 + fr)*64 + kk*32 + fk*8));
      #pragma unroll
      for (int j = 0; j < 4; ++j)
        bfg[j] = *(const bf16x8*)(Bs + ((wc*64 + j*16 + fr)*64 + kk*32 + fk*8));
      #pragma unroll
      for (int i = 0; i < 4; ++i)
        #pragma unroll
        for (int j = 0; j < 4; ++j)
          acc[i][j] = __builtin_amdgcn_mfma_f32_16x16x32_bf16(af[i], bfg[j], acc[i][j], 0, 0, 0);
    }
    __syncthreads();
  }
}

#define GEMM_PROLOGUE() \
  __shared__ __align__(16) u16 As[128*64]; \
  __shared__ __align__(16) u16 Bs[128*64]; \
  f32x4 acc[4][4] = {}; \
  const int tid = threadIdx.x; \
  const int lane = tid & 63, w = tid >> 6; \
  const int wr = w >> 1, wc = w & 1; \
  const int fr = lane & 15, fk = lane >> 4; \
  (void)lane;

__global__ __launch_bounds__(256) void k_qkv(const u16* __restrict__ hT,
                                             const u16* __restrict__ wq,
                                             const float* __restrict__ bqkv,
                                             u16* __restrict__ qT, u16* __restrict__ kT,
                                             u16* __restrict__ vb) {
  GEMM_PROLOGUE();
  const int bz = blockIdx.z;
  const int rowBase = blockIdx.y * 128, colBase = blockIdx.x * 128;
  gemm_nt_core(hT + ((size_t)bz*4096 + rowBase)*512, 512,
               wq + (size_t)colBase*512, 512, 512, As, Bs, acc);
  #pragma unroll
  for (int i = 0; i < 4; ++i)
    #pragma unroll
    for (int j = 0; j < 4; ++j)
      #pragma unroll
      for (int r = 0; r < 4; ++r) {
        int n = rowBase + wr*64 + i*16 + fk*4 + r;
        int o = colBase + wc*64 + j*16 + fr;
        u16 u = f2bf(acc[i][j][r] + bqkv[o]);
        if (o < 512)       qT[((size_t)bz*4096 + n)*512 + o]          = u;
        else if (o < 1024) kT[((size_t)bz*4096 + n)*512 + (o - 512)]  = u;
        else               vb[((size_t)bz*512 + (o - 1024))*4096 + n] = u;
      }
}

// ------------- Scores: 256x256, BK=64, 4-phase counted-vmcnt pipeline -----------
// 8 waves (2M x 4N), 1 block/CU, LDS 128KB (2 dbuf x {A,B} x 2 k-halves x 16KB).
// Stage unit = one k-half of one operand (16KB, 2 gload16/thread).
// During tile t: phases stage t+1's units [A0,B0,A1,B1] into buf (t+1)&1.
// vmcnt(4) before phases 0 and 2 only (never 0 in loop). Raw s_barrier per phase.
// LDS plane [256 rows][4 slots x 16B], slot swizzled: slot = fk ^ ((fr>>1)&3).
DEVINL void stage_unit(const u16* __restrict__ src, int kofs, u16* plane, int tid) {
  #pragma unroll
  for (int q = 0; q < 2; ++q) {
    int c = q*512 + tid;               // 1024 chunks of 16B
    int row = c >> 2, slot = c & 3;
    int kc = slot ^ ((row >> 1) & 3);  // inverse swizzle on global source
    gload16(src + (size_t)row*512 + kofs + kc*8, plane + c*8);
  }
}

__global__ __launch_bounds__(512) void k_scores256(const u16* __restrict__ qT,
                                                   const u16* __restrict__ kT,
                                                   u16* __restrict__ E,
                                                   float* __restrict__ lsum) {
  __shared__ __align__(16) u16 As[2][2][256*32];   // 64 KB
  __shared__ __align__(16) u16 Bs[2][2][256*32];   // 64 KB
  f32x4 acc[8][4] = {};
  const int tid = threadIdx.x;
  const int lane = tid & 63, w = tid >> 6;
  const int wr = w >> 2, wc = w & 3;               // 2M x 4N wave grid
  const int fr = lane & 15, fk = lane >> 4;
  const int swz = fk ^ ((fr >> 1) & 3);
  const int bz = blockIdx.z;
  // T1: bijective XCD swizzle (256 blocks/slice, 32 per XCD, grouped by Q-row)
  int f = blockIdx.y * 16 + blockIdx.x;
  int L = (f & 7) * 32 + (f >> 3);
  const int rowBase = (L >> 4) * 256, colBase = (L & 15) * 256;
  const u16* qa = qT + (size_t)bz*4096*512 + (size_t)rowBase*512;
  const u16* ka = kT + (size_t)bz*4096*512 + (size_t)colBase*512;
  u16* Eb = E + (size_t)bz*4096*4096;
  float* ls = lsum + (size_t)bz*4096;

  // prologue: tile 0, all 4 units (8 loads/thread outstanding)
  stage_unit(qa, 0,  As[0][0], tid);
  stage_unit(ka, 0,  Bs[0][0], tid);
  stage_unit(qa, 32, As[0][1], tid);
  stage_unit(ka, 32, Bs[0][1], tid);

  const int NT = 8;   // K=512, BK=64
  #pragma unroll 1
  for (int t = 0; t < NT; ++t) {
    const int cur = t & 1, nxt = cur ^ 1;
    const int ktn = ((t + 1) & (NT - 1)) * 64;   // wrap: last tile stages dummy
    bf16x8 af[8], bfr[2];

    // ---- phase 0: kk=0, cols j0,j1 ----
    asm volatile("s_waitcnt vmcnt(4)" ::: "memory");
    __builtin_amdgcn_s_barrier();
    {
      const u16* Ap = As[cur][0];
      #pragma unroll
      for (int i = 0; i < 8; ++i)
        af[i] = *(const bf16x8*)(Ap + (wr*128 + i*16 + fr)*32 + swz*8);
      const u16* Bp = Bs[cur][0];
      bfr[0] = *(const bf16x8*)(Bp + (wc*64 + 0*16 + fr)*32 + swz*8);
      bfr[1] = *(const bf16x8*)(Bp + (wc*64 + 1*16 + fr)*32 + swz*8);
    }
    stage_unit(qa, ktn, As[nxt][0], tid);
    __builtin_amdgcn_s_setprio(1);
    #pragma unroll
    for (int i = 0; i < 8; ++i) {
      acc[i][0] = __builtin_amdgcn_mfma_f32_16x16x32_bf16(af[i], bfr[0], acc[i][0], 0, 0, 0);
      acc[i][1] = __builtin_amdgcn_mfma_f32_16x16x32_bf16(af[i], bfr[1], acc[i][1], 0, 0, 0);
    }
    __builtin_amdgcn_s_setprio(0);

    // ---- phase 1: kk=0, cols j2,j3 ----
    __builtin_amdgcn_s_barrier();
    {
      const u16* Bp = Bs[cur][0];
      bfr[0] = *(const bf16x8*)(Bp + (wc*64 + 2*16 + fr)*32 + swz*8);
      bfr[1] = *(const bf16x8*)(Bp + (wc*64 + 3*16 + fr)*32 + swz*8);
    }
    stage_unit(ka, ktn, Bs[nxt][0], tid);
    __builtin_amdgcn_s_setprio(1);
    #pragma unroll
    for (int i = 0; i < 8; ++i) {
      acc[i][2] = __builtin_amdgcn_mfma_f32_16x16x32_bf16(af[i], bfr[0], acc[i][2], 0, 0, 0);
      acc[i][3] = __builtin_amdgcn_mfma_f32_16x16x32_bf16(af[i], bfr[1], acc[i][3], 0, 0, 0);
    }
    __builtin_amdgcn_s_setprio(0);

    // ---- phase 2: kk=1, cols j0,j1 ----
    asm volatile("s_waitcnt vmcnt(4)" ::: "memory");
    __builtin_amdgcn_s_barrier();
    {
      const u16* Ap = As[cur][1];
      #pragma unroll
      for (int i = 0; i < 8; ++i)
        af[i] = *(const bf16x8*)(Ap + (wr*128 + i*16 + fr)*32 + swz*8);
      const u16* Bp = Bs[cur][1];
      bfr[0] = *(const bf16x8*)(Bp + (wc*64 + 0*16 + fr)*32 + swz*8);
      bfr[1] = *(const bf16x8*)(Bp + (wc*64 + 1*16 + fr)*32 + swz*8);
    }
    stage_unit(qa, ktn + 32, As[nxt][1], tid);
    __builtin_amdgcn_s_setprio(1);
    #pragma unroll
    for (int i = 0; i < 8; ++i) {
      acc[i][0] = __builtin_amdgcn_mfma_f32_16x16x32_bf16(af[i], bfr[0], acc[i][0], 0, 0, 0);
      acc[i][1] = __builtin_amdgcn_mfma_f32_16x16x32_bf16(af[i], bfr[1], acc[i][1], 0, 0, 0);
    }
    __builtin_amdgcn_s_setprio(0);

    // ---- phase 3: kk=1, cols j2,j3 ----
    __builtin_amdgcn_s_barrier();
    {
      const u16* Bp = Bs[cur][1];
      bfr[0] = *(const bf16x8*)(Bp + (wc*64 + 2*16 + fr)*32 + swz*8);
      bfr[1] = *(const bf16x8*)(Bp + (wc*64 + 3*16 + fr)*32 + swz*8);
    }
    stage_unit(ka, ktn + 32, Bs[nxt][1], tid);
    __builtin_amdgcn_s_setprio(1);
    #pragma unroll
    for (int i = 0; i < 8; ++i) {
      acc[i][2] = __builtin_amdgcn_mfma_f32_16x16x32_bf16(af[i], bfr[0], acc[i][2], 0, 0, 0);
      acc[i][3] = __builtin_amdgcn_mfma_f32_16x16x32_bf16(af[i], bfr[1], acc[i][3], 0, 0, 0);
    }
    __builtin_amdgcn_s_setprio(0);
  }

  const float scale = 0.04419417382415922f;  // 512^-0.5
  #pragma unroll
  for (int i = 0; i < 8; ++i)
    #pragma unroll
    for (int r = 0; r < 4; ++r) {
      int nl = rowBase + wr*128 + i*16 + fk*4 + r;
      float s = 0.f;
      #pragma unroll
      for (int j = 0; j < 4; ++j) {
        int m = colBase + wc*64 + j*16 + fr;
        float e = __expf(acc[i][j][r] * scale);
        Eb[(size_t)nl*4096 + m] = f2bf(e);
        s += e;
      }
      s += __shfl_xor(s, 1, 64);
      s += __shfl_xor(s, 2, 64);
      s += __shfl_xor(s, 4, 64);
      s += __shfl_xor(s, 8, 64);
      if (fr == 0) atomicAdd(&ls[nl], s);
    }
}

// Old 128^2 scores kernel kept for the chunked fallback path.
__global__ __launch_bounds__(256) void k_scores(const u16* __restrict__ qT,
                                                const u16* __restrict__ kT,
                                                u16* __restrict__ E,
                                                float* __restrict__ lsum,
                                                long long qkStride, long long eStride,
                                                int lsStride) {
  GEMM_PROLOGUE();
  const int bz = blockIdx.z;
  const u16* q0 = qT + (size_t)bz * qkStride;
  const u16* k0 = kT + (size_t)bz * qkStride;
  u16* Eb = E + (size_t)bz * eStride;
  float* ls = lsum + (size_t)bz * lsStride;
  const int rowBase = blockIdx.y * 128, colBase = blockIdx.x * 128;
  gemm_nt_core(q0 + (size_t)rowBase*512, 512, k0 + (size_t)colBase*512, 512,
               512, As, Bs, acc);
  const float scale = 0.04419417382415922f;
  #pragma unroll
  for (int i = 0; i < 4; ++i)
    #pragma unroll
    for (int r = 0; r < 4; ++r) {
      int nl = rowBase + wr*64 + i*16 + fk*4 + r;
      float s = 0.f;
      #pragma unroll
      for (int j = 0; j < 4; ++j) {
        int m = colBase + wc*64 + j*16 + fr;
        float e = __expf(acc[i][j][r] * scale);
        Eb[(size_t)nl*4096 + m] = f2bf(e);
        s += e;
      }
      s += __shfl_xor(s, 1, 64);
      s += __shfl_xor(s, 2, 64);
      s += __shfl_xor(s, 4, 64);
      s += __shfl_xor(s, 8, 64);
      if (fr == 0) atomicAdd(&ls[nl], s);
    }
}

// PV: out[nl][d] = (sum_m E[nl][m] * v[d][m]) / lsum[nl].
__global__ __launch_bounds__(256) void k_pv(const u16* __restrict__ E,
                                            const u16* __restrict__ vb,
                                            const float* __restrict__ lsum,
                                            u16* __restrict__ attnb,
                                            long long eStride, long long vStride,
                                            int lsStride, long long aStride,
                                            int doSwz) {
  GEMM_PROLOGUE();
  const int bz = blockIdx.z;
  const u16* Eb = E + (size_t)bz * eStride;
  const u16* vbb = vb + (size_t)bz * vStride;
  const float* ls = lsum + (size_t)bz * lsStride;
  u16* ab = attnb + (size_t)bz * aStride;
  int rowT = blockIdx.y, colT = blockIdx.x;
  if (doSwz) {             // T1: 128 blocks/slice -> 16 per XCD, grouped by E-row
    int f = blockIdx.y * 4 + blockIdx.x;
    int L = (f & 7) * 16 + (f >> 3);
    rowT = L >> 2; colT = L & 3;
  }
  const int rowBase = rowT * 128, colBase = colT * 128;
  gemm_nt_core(Eb + (size_t)rowBase*4096, 4096, vbb + (size_t)colBase*4096, 4096,
               4096, As, Bs, acc);
  #pragma unroll
  for (int i = 0; i < 4; ++i)
    #pragma unroll
    for (int r = 0; r < 4; ++r) {
      int nl = rowBase + wr*64 + i*16 + fk*4 + r;
      float rinv = 1.0f / ls[nl];
      #pragma unroll
      for (int j = 0; j < 4; ++j) {
        int d = colBase + wc*64 + j*16 + fr;
        ab[(size_t)nl*512 + d] = f2bf(acc[i][j][r] * rinv);
      }
    }
}

__global__ __launch_bounds__(256) void k_proj(const u16* __restrict__ wp,
                                              const u16* __restrict__ attn,
                                              const float* __restrict__ bproj,
                                              const float* __restrict__ x,
                                              float* __restrict__ out) {
  GEMM_PROLOGUE();
  const int bz = blockIdx.z;
  const int rowBase = blockIdx.y * 128, colBase = blockIdx.x * 128;
  gemm_nt_core(wp + (size_t)rowBase*512, 512,
               attn + ((size_t)bz*4096 + colBase)*512, 512, 512, As, Bs, acc);
  #pragma unroll
  for (int i = 0; i < 4; ++i)
    #pragma unroll
    for (int j = 0; j < 4; ++j)
      #pragma unroll
      for (int r = 0; r < 4; ++r) {
        int o = rowBase + wr*64 + i*16 + fk*4 + r;
        int n = colBase + wc*64 + j*16 + fr;
        size_t idx = ((size_t)bz*512 + o)*4096 + n;
        out[idx] = acc[i][j][r] + bproj[o] + x[idx];
      }
}

extern "C" void kernel_launch(void* const* d_in, const int* in_sizes, int n_in,
                              void* d_out, int out_size, void* d_ws, size_t ws_size,
                              hipStream_t stream) {
  const float* x      = (const float*)d_in[0];
  const float* gamma  = (const float*)d_in[1];
  const float* beta   = (const float*)d_in[2];
  const float* w_qkv  = (const float*)d_in[3];
  const float* b_qkv  = (const float*)d_in[4];
  const float* w_proj = (const float*)d_in[5];
  const float* b_proj = (const float*)d_in[6];
  float* out = (float*)d_out;
  char* ws = (char*)d_ws;

  size_t off = 0;
  u16* wqb   = (u16*)(ws + off); off += (size_t)1536*512*2;
  u16* wpb   = (u16*)(ws + off); off += (size_t)512*512*2;
  float* stats = (float*)(ws + off); off += 256;
  float* psum  = (float*)(ws + off); off += 512*4;
  float* psumsq= (float*)(ws + off); off += 512*4;
  float* lsum  = (float*)(ws + off); off += (size_t)4*4096*4;
  u16* hT    = (u16*)(ws + off);                      // reused as attn_out after QKV
  u16* attn  = hT;
  off += (size_t)4*4096*512*2;
  u16* qT    = (u16*)(ws + off); off += (size_t)4*4096*512*2;
  u16* kT    = (u16*)(ws + off); off += (size_t)4*4096*512*2;
  u16* vb    = (u16*)(ws + off); off += (size_t)4*4096*512*2;
  u16* E     = (u16*)(ws + off);
  size_t avail = ws_size > off ? ws_size - off : 0;
  const size_t fullE = (size_t)4*4096*4096*2;

  gn_stats1_k<<<512, 256, 0, stream>>>(x, psum, psumsq);
  gn_stats2_k<<<1, 32, 0, stream>>>(psum, psumsq, stats);
  gn_apply_k<<<dim3(64, 8, 4), 256, 0, stream>>>(x, gamma, beta, stats, hT);
  cast_w_k<<<3072, 256, 0, stream>>>(w_qkv, w_proj, wqb, wpb);
  k_qkv<<<dim3(12, 32, 4), 256, 0, stream>>>(hT, wqb, b_qkv, qT, kT, vb);

  if (avail >= fullE) {
    (void)hipMemsetAsync(lsum, 0, (size_t)4*4096*sizeof(float), stream);
    k_scores256<<<dim3(16, 16, 4), 512, 0, stream>>>(qT, kT, E, lsum);
    k_pv<<<dim3(4, 32, 4), 256, 0, stream>>>(
        E, vb, lsum, attn, 4096LL*4096, 512LL*4096, 4096, 4096LL*512, 1);
  } else {
    int CH = 4096;
    while (CH > 128 && (size_t)CH*4096*2 > avail) CH >>= 1;
    for (int b = 0; b < 4; ++b) {
      for (int c0 = 0; c0 < 4096; c0 += CH) {
        (void)hipMemsetAsync(lsum, 0, (size_t)CH * sizeof(float), stream);
        k_scores<<<dim3(32, CH/128, 1), 256, 0, stream>>>(
            qT + ((size_t)b*4096 + c0)*512, kT + (size_t)b*4096*512, E, lsum, 0, 0, 0);
        k_pv<<<dim3(4, CH/128, 1), 256, 0, stream>>>(
            E, vb + (size_t)b*512*4096, lsum, attn + ((size_t)b*4096 + c0)*512, 0, 0, 0, 0, 0);
      }
    }
  }
  k_proj<<<dim3(32, 4, 4), 256, 0, stream>>>(wpb, attn, b_proj, x, out);
}